// Round 5
// baseline (292.116 us; speedup 1.0000x reference)
//
#include <hip/hip_runtime.h>

#define N_NODES 100000
#define N_EDGES 1600000
#define D 64
#define SCAN_BLOCK 1024
#define N_CHUNKS 98          // 98*1024 = 100352 >= N_NODES
#define NCOPY 8
#define CSTRIDE 100352       // per-copy counter stride (ints)
#define HIST_EPT 8           // block spans 2048 edges = 1<<11
#define FILL_EPT 4

// ---- ws layout (4-byte units), total 20,011,904 B (fits proven ws >= 20,400,640 B) ----
#define WS_CNT      0                      // [NCOPY*CSTRIDE] counts -> bases (zeroed)
#define WS_TOTAL    (NCOPY*CSTRIDE)        // [100000] node degree
#define WS_ROWPTR   (WS_TOTAL + 100000)    // [100001] (+pad)
#define WS_PARTIAL  (WS_ROWPTR + 100032)   // [128]
#define WS_RANK     (WS_PARTIAL + 128)     // ushort[1600000] = 800000 ints
#define WS_PAIRS    (WS_RANK + 800000)     // int2[1600000]

// ---------------- CSR build ----------------

// Privatized histogram: copy = blockIdx&7 -> each node's ~16 ops spread over
// 8 distinct addresses in distinct 32B sectors (R3 falsified latency-bound;
// serialization is per-address/sector at the memory-side atomic unit).
__global__ __launch_bounds__(256) void k_hist_rank(
    const int* __restrict__ esrc, int* __restrict__ cnt,
    unsigned short* __restrict__ rank)
{
    int* mycnt = cnt + (blockIdx.x & (NCOPY - 1)) * CSTRIDE;
    int base = blockIdx.x * (256 * HIST_EPT) + threadIdx.x;
    int s[HIST_EPT];
    #pragma unroll
    for (int i = 0; i < HIST_EPT; ++i) {
        int e = base + i * 256;
        s[i] = (e < N_EDGES) ? esrc[e] : -1;
    }
    int r[HIST_EPT];
    #pragma unroll
    for (int i = 0; i < HIST_EPT; ++i)
        if (s[i] >= 0) r[i] = atomicAdd(&mycnt[s[i]], 1);
    #pragma unroll
    for (int i = 0; i < HIST_EPT; ++i) {
        int e = base + i * 256;
        if (e < N_EDGES) rank[e] = (unsigned short)r[i];
    }
}

// Per node: exclusive scan over the 8 copy-counts (written back as bases),
// node total, and per-chunk partial sums (block reduction).
__global__ __launch_bounds__(SCAN_BLOCK) void k_copy_scan(
    int* __restrict__ cnt, int* __restrict__ total, int* __restrict__ partial)
{
    __shared__ int sred[16];
    int t = threadIdx.x;
    int i = blockIdx.x * SCAN_BLOCK + t;
    int tot = 0;
    if (i < N_NODES) {
        int c[NCOPY];
        #pragma unroll
        for (int k = 0; k < NCOPY; ++k) c[k] = cnt[k * CSTRIDE + i];
        int run = 0;
        #pragma unroll
        for (int k = 0; k < NCOPY; ++k) {
            cnt[k * CSTRIDE + i] = run;
            run += c[k];
        }
        tot = run;
        total[i] = run;
    }
    int v = tot;
    #pragma unroll
    for (int off = 32; off; off >>= 1) v += __shfl_down(v, off, 64);
    if ((t & 63) == 0) sred[t >> 6] = v;
    __syncthreads();
    if (t < 16) {
        int w = sred[t];
        #pragma unroll
        for (int off = 8; off; off >>= 1) w += __shfl_down(w, off, 16);
        if (t == 0) partial[blockIdx.x] = w;
    }
}

__global__ __launch_bounds__(128) void k_scan_partial(
    int* __restrict__ partial, int* __restrict__ row_ptr)
{
    __shared__ int w0;
    int t = threadIdx.x;
    int lane = t & 63;
    int v = (t < N_CHUNKS) ? partial[t] : 0;
    int s = v;
    #pragma unroll
    for (int off = 1; off < 64; off <<= 1) {
        int y = __shfl_up(s, off, 64);
        if (lane >= off) s += y;
    }
    if (t == 63) w0 = s;
    __syncthreads();
    if (t >= 64) s += w0;
    if (t < N_CHUNKS) partial[t] = s - v;
    if (t == N_CHUNKS - 1) row_ptr[N_NODES] = s;
}

__global__ __launch_bounds__(SCAN_BLOCK) void k_chunk_scan(
    const int* __restrict__ total, const int* __restrict__ partial,
    int* __restrict__ row_ptr)
{
    __shared__ int wsum[16];
    int t = threadIdx.x;
    int lane = t & 63, wid = t >> 6;
    int i = blockIdx.x * SCAN_BLOCK + t;
    int v = (i < N_NODES) ? total[i] : 0;
    int s = v;
    #pragma unroll
    for (int off = 1; off < 64; off <<= 1) {
        int y = __shfl_up(s, off, 64);
        if (lane >= off) s += y;
    }
    if (lane == 63) wsum[wid] = s;
    __syncthreads();
    if (t < 16) {
        int w = wsum[t];
        #pragma unroll
        for (int off = 1; off < 16; off <<= 1) {
            int y = __shfl_up(w, off, 16);
            if (t >= off) w += y;
        }
        wsum[t] = w;
    }
    __syncthreads();
    int prefix = wid ? wsum[wid - 1] : 0;
    if (i < N_NODES) row_ptr[i] = partial[blockIdx.x] + prefix + s - v;
}

// pos = row_ptr[src] + base[src,copy] + rank ; copy recomputed as (e>>11)&7.
__global__ __launch_bounds__(256) void k_fill_rank(
    const int* __restrict__ esrc, const int* __restrict__ edst,
    const float* __restrict__ eval_, const int* __restrict__ row_ptr,
    const int* __restrict__ bases, const unsigned short* __restrict__ rank,
    int2* __restrict__ pairs)
{
    int base = blockIdx.x * (256 * FILL_EPT) + threadIdx.x;
    int pos[FILL_EPT]; int2 pv[FILL_EPT];
    #pragma unroll
    for (int i = 0; i < FILL_EPT; ++i) {
        int e = base + i * 256;
        if (e < N_EDGES) {
            int s = esrc[e];
            int copy = (e >> 11) & (NCOPY - 1);
            pos[i] = row_ptr[s] + bases[copy * CSTRIDE + s] + (int)rank[e];
            pv[i] = make_int2(edst[e], __float_as_int(eval_[e]));
        } else pos[i] = -1;
    }
    #pragma unroll
    for (int i = 0; i < FILL_EPT; ++i)
        if (pos[i] >= 0) pairs[pos[i]] = pv[i];
}

// ---------------- aggregation: rep = agg + eps*x ----------------
// Masked 16-wide batches: every row keeps 16 loads in flight regardless of
// degree (R3's 8/4/1 tails left half the rows at low MLP).
#define GATHER_BLOCKS 1563

__global__ __launch_bounds__(256) void k_gather(
    const float* __restrict__ x, const int* __restrict__ row_ptr,
    const int2* __restrict__ pairs, const float* __restrict__ epsilon,
    float* __restrict__ rep)
{
    int gw = (blockIdx.x * 256 + threadIdx.x) >> 6;
    int lane = threadIdx.x & 63;
    int nw = gridDim.x * 4;
    float eps = epsilon[0];
    for (int row = gw; row < N_NODES; row += nw) {
        int start = __builtin_amdgcn_readfirstlane(row_ptr[row]);
        int end   = __builtin_amdgcn_readfirstlane(row_ptr[row + 1]);
        float acc = 0.0f;
        for (int j = start; j < end; j += 16) {
            int2 p[16];
            #pragma unroll
            for (int u = 0; u < 16; ++u) {
                int idx = j + u;
                p[u] = pairs[idx < end ? idx : end - 1];
            }
            float a[16];
            #pragma unroll
            for (int u = 0; u < 16; ++u)
                a[u] = x[(size_t)p[u].x * D + lane];
            #pragma unroll
            for (int u = 0; u < 16; ++u) {
                float v = (j + u < end) ? __int_as_float(p[u].y) : 0.0f;
                acc += v * a[u];
            }
        }
        size_t base = (size_t)row * D;
        rep[base + lane] = acc + eps * x[base + lane];
    }
}

// ---------------- out = rep @ W + bias ----------------
#define GEMM_TM 64
__global__ __launch_bounds__(256) void k_gemm(
    const float* __restrict__ rep, const float* __restrict__ weight,
    const float* __restrict__ bias, float* __restrict__ out)
{
    __shared__ float rep_s[GEMM_TM * 68];
    __shared__ float Ws[D * D];
    int t = threadIdx.x;
    {
        const float4* w4 = (const float4*)weight;
        float4* s4 = (float4*)Ws;
        #pragma unroll
        for (int i = 0; i < (D * D / 4) / 256; ++i)
            s4[t + i * 256] = w4[t + i * 256];
    }
    int row0 = blockIdx.x * GEMM_TM;
    {
        const float4* r4 = (const float4*)rep;
        #pragma unroll
        for (int i = 0; i < 4; ++i) {
            int f = t + i * 256;
            int rr = f >> 4, kk4 = f & 15;
            float4 v = (row0 + rr < N_NODES) ? r4[(size_t)(row0 + rr) * 16 + kk4]
                                             : make_float4(0.f, 0.f, 0.f, 0.f);
            rep_s[rr * 68 + kk4 * 4 + 0] = v.x;
            rep_s[rr * 68 + kk4 * 4 + 1] = v.y;
            rep_s[rr * 68 + kk4 * 4 + 2] = v.z;
            rep_s[rr * 68 + kk4 * 4 + 3] = v.w;
        }
    }
    __syncthreads();

    int tx = t & 15, ty = t >> 4;
    float4 b4 = ((const float4*)bias)[tx];
    float acc[4][4];
    #pragma unroll
    for (int i = 0; i < 4; ++i) {
        acc[i][0] = b4.x; acc[i][1] = b4.y; acc[i][2] = b4.z; acc[i][3] = b4.w;
    }
    #pragma unroll 4
    for (int k4 = 0; k4 < 16; ++k4) {
        float4 rv[4];
        #pragma unroll
        for (int i = 0; i < 4; ++i)
            rv[i] = *(const float4*)&rep_s[(ty * 4 + i) * 68 + k4 * 4];
        #pragma unroll
        for (int kk = 0; kk < 4; ++kk) {
            float4 wv = *(const float4*)&Ws[(k4 * 4 + kk) * D + tx * 4];
            #pragma unroll
            for (int i = 0; i < 4; ++i) {
                float r = ((const float*)&rv[i])[kk];
                acc[i][0] += r * wv.x;
                acc[i][1] += r * wv.y;
                acc[i][2] += r * wv.z;
                acc[i][3] += r * wv.w;
            }
        }
    }
    #pragma unroll
    for (int i = 0; i < 4; ++i) {
        int row = row0 + ty * 4 + i;
        if (row < N_NODES)
            *(float4*)&out[(size_t)row * D + tx * 4] =
                make_float4(acc[i][0], acc[i][1], acc[i][2], acc[i][3]);
    }
}

extern "C" void kernel_launch(void* const* d_in, const int* in_sizes, int n_in,
                              void* d_out, int out_size, void* d_ws, size_t ws_size,
                              hipStream_t stream) {
    const float* x    = (const float*)d_in[0];
    const int*   esrc = (const int*)  d_in[1];
    const int*   edst = (const int*)  d_in[2];
    const float* ev   = (const float*)d_in[3];
    const float* w    = (const float*)d_in[4];
    const float* eps  = (const float*)d_in[5];
    const float* bias = (const float*)d_in[6];

    float* out = (float*)d_out;
    float* rep = out + (size_t)N_NODES * D;

    int* ws      = (int*)d_ws;
    int* cnt     = ws + WS_CNT;
    int* total   = ws + WS_TOTAL;
    int* row_ptr = ws + WS_ROWPTR;
    int* partial = ws + WS_PARTIAL;
    unsigned short* rank = (unsigned short*)(ws + WS_RANK);
    int2* pairs  = (int2*)(ws + WS_PAIRS);

    hipMemsetAsync(cnt, 0, (size_t)NCOPY * CSTRIDE * sizeof(int), stream);

    int hgrid = (N_EDGES + 256 * HIST_EPT - 1) / (256 * HIST_EPT);
    k_hist_rank<<<hgrid, 256, 0, stream>>>(esrc, cnt, rank);
    k_copy_scan<<<N_CHUNKS, SCAN_BLOCK, 0, stream>>>(cnt, total, partial);
    k_scan_partial<<<1, 128, 0, stream>>>(partial, row_ptr);
    k_chunk_scan<<<N_CHUNKS, SCAN_BLOCK, 0, stream>>>(total, partial, row_ptr);
    int fgrid = (N_EDGES + 256 * FILL_EPT - 1) / (256 * FILL_EPT);
    k_fill_rank<<<fgrid, 256, 0, stream>>>(esrc, edst, ev, row_ptr, cnt, rank, pairs);
    k_gather<<<GATHER_BLOCKS, 256, 0, stream>>>(x, row_ptr, pairs, eps, rep);
    k_gemm<<<(N_NODES + GEMM_TM - 1) / GEMM_TM, 256, 0, stream>>>(rep, w, bias, out);
}

// Round 6
// 272.549 us; speedup vs baseline: 1.0718x; 1.0718x over previous
//
#include <hip/hip_runtime.h>

#define N_NODES 100000
#define N_EDGES 1600000
#define D 64
#define SCAN_BLOCK 1024
#define N_CHUNKS 98          // 98*1024 = 100352 >= N_NODES
#define NCOPY 8
#define CSTRIDE 100352       // per-copy counter stride (ints)
#define HIST_EPT 4           // block spans 1024 edges = 1<<10
#define HIST_SPAN_SHIFT 10
#define FILL_EPT 4

// ---- ws layout (4-byte units), total 20,011,904 B (proven ws >= 20,400,640 B) ----
#define WS_CNT      0                      // [NCOPY*CSTRIDE] counts -> absolute bases
#define WS_TOTAL    (NCOPY*CSTRIDE)        // [100000] node degree
#define WS_ROWPTR   (WS_TOTAL + 100000)    // [100001] (+pad)
#define WS_PARTIAL  (WS_ROWPTR + 100032)   // [128]
#define WS_RANK     (WS_PARTIAL + 128)     // ushort[1600000] = 800000 ints
#define WS_PAIRS    (WS_RANK + 800000)     // int2[1600000]

// ---------------- CSR build ----------------

// Privatized histogram (copy = blockIdx&7). EPT=4: grid 1563 blocks keeps
// ~24 waves/CU resident with 4 atomic-returns in flight each — tests whether
// any concurrency level moves the ~70us wall (model: per-channel RMW rate).
__global__ __launch_bounds__(256) void k_hist_rank(
    const int* __restrict__ esrc, int* __restrict__ cnt,
    unsigned short* __restrict__ rank)
{
    int* mycnt = cnt + (blockIdx.x & (NCOPY - 1)) * CSTRIDE;
    int base = blockIdx.x * (256 * HIST_EPT) + threadIdx.x;
    int s[HIST_EPT];
    #pragma unroll
    for (int i = 0; i < HIST_EPT; ++i) {
        int e = base + i * 256;
        s[i] = (e < N_EDGES) ? esrc[e] : -1;
    }
    int r[HIST_EPT];
    #pragma unroll
    for (int i = 0; i < HIST_EPT; ++i)
        if (s[i] >= 0) r[i] = atomicAdd(&mycnt[s[i]], 1);
    #pragma unroll
    for (int i = 0; i < HIST_EPT; ++i) {
        int e = base + i * 256;
        if (e < N_EDGES) rank[e] = (unsigned short)r[i];
    }
}

// Per node: exclusive scan over the 8 copy-counts (written back in place),
// node total, per-chunk partial sums.
__global__ __launch_bounds__(SCAN_BLOCK) void k_copy_scan(
    int* __restrict__ cnt, int* __restrict__ total, int* __restrict__ partial)
{
    __shared__ int sred[16];
    int t = threadIdx.x;
    int i = blockIdx.x * SCAN_BLOCK + t;
    int tot = 0;
    if (i < N_NODES) {
        int c[NCOPY];
        #pragma unroll
        for (int k = 0; k < NCOPY; ++k) c[k] = cnt[k * CSTRIDE + i];
        int run = 0;
        #pragma unroll
        for (int k = 0; k < NCOPY; ++k) {
            cnt[k * CSTRIDE + i] = run;
            run += c[k];
        }
        tot = run;
        total[i] = run;
    }
    int v = tot;
    #pragma unroll
    for (int off = 32; off; off >>= 1) v += __shfl_down(v, off, 64);
    if ((t & 63) == 0) sred[t >> 6] = v;
    __syncthreads();
    if (t < 16) {
        int w = sred[t];
        #pragma unroll
        for (int off = 8; off; off >>= 1) w += __shfl_down(w, off, 16);
        if (t == 0) partial[blockIdx.x] = w;
    }
}

__global__ __launch_bounds__(128) void k_scan_partial(
    int* __restrict__ partial, int* __restrict__ row_ptr)
{
    __shared__ int w0;
    int t = threadIdx.x;
    int lane = t & 63;
    int v = (t < N_CHUNKS) ? partial[t] : 0;
    int s = v;
    #pragma unroll
    for (int off = 1; off < 64; off <<= 1) {
        int y = __shfl_up(s, off, 64);
        if (lane >= off) s += y;
    }
    if (t == 63) w0 = s;
    __syncthreads();
    if (t >= 64) s += w0;
    if (t < N_CHUNKS) partial[t] = s - v;
    if (t == N_CHUNKS - 1) row_ptr[N_NODES] = s;
}

// row_ptr[i] = global exclusive scan of degree; ALSO folds row_ptr into the
// 8 per-copy bases so fill needs only ONE random gather (R4 regression fix).
__global__ __launch_bounds__(SCAN_BLOCK) void k_chunk_scan(
    const int* __restrict__ total, const int* __restrict__ partial,
    int* __restrict__ row_ptr, int* __restrict__ bases)
{
    __shared__ int wsum[16];
    int t = threadIdx.x;
    int lane = t & 63, wid = t >> 6;
    int i = blockIdx.x * SCAN_BLOCK + t;
    int v = (i < N_NODES) ? total[i] : 0;
    int s = v;
    #pragma unroll
    for (int off = 1; off < 64; off <<= 1) {
        int y = __shfl_up(s, off, 64);
        if (lane >= off) s += y;
    }
    if (lane == 63) wsum[wid] = s;
    __syncthreads();
    if (t < 16) {
        int w = wsum[t];
        #pragma unroll
        for (int off = 1; off < 16; off <<= 1) {
            int y = __shfl_up(w, off, 16);
            if (t >= off) w += y;
        }
        wsum[t] = w;
    }
    __syncthreads();
    int prefix = wid ? wsum[wid - 1] : 0;
    if (i < N_NODES) {
        int rp = partial[blockIdx.x] + prefix + s - v;
        row_ptr[i] = rp;
        #pragma unroll
        for (int k = 0; k < NCOPY; ++k) bases[k * CSTRIDE + i] += rp;
    }
}

// pos = bases[copy][src] + rank ; copy recomputed from edge index.
__global__ __launch_bounds__(256) void k_fill_rank(
    const int* __restrict__ esrc, const int* __restrict__ edst,
    const float* __restrict__ eval_, const int* __restrict__ bases,
    const unsigned short* __restrict__ rank, int2* __restrict__ pairs)
{
    int base = blockIdx.x * (256 * FILL_EPT) + threadIdx.x;
    int pos[FILL_EPT]; int2 pv[FILL_EPT];
    #pragma unroll
    for (int i = 0; i < FILL_EPT; ++i) {
        int e = base + i * 256;
        if (e < N_EDGES) {
            int s = esrc[e];
            int copy = (e >> HIST_SPAN_SHIFT) & (NCOPY - 1);
            pos[i] = bases[copy * CSTRIDE + s] + (int)rank[e];
            pv[i] = make_int2(edst[e], __float_as_int(eval_[e]));
        } else pos[i] = -1;
    }
    #pragma unroll
    for (int i = 0; i < FILL_EPT; ++i)
        if (pos[i] >= 0) pairs[pos[i]] = pv[i];
}

// ---------------- aggregation: rep = agg + eps*x ----------------
// R3-proven structure: 8-wide unrolled main loop + 4/1 tails.
#define GATHER_BLOCKS 1563

__global__ __launch_bounds__(256) void k_gather(
    const float* __restrict__ x, const int* __restrict__ row_ptr,
    const int2* __restrict__ pairs, const float* __restrict__ epsilon,
    float* __restrict__ rep)
{
    int gw = (blockIdx.x * 256 + threadIdx.x) >> 6;
    int lane = threadIdx.x & 63;
    int nw = gridDim.x * 4;
    float eps = epsilon[0];
    for (int row = gw; row < N_NODES; row += nw) {
        int start = __builtin_amdgcn_readfirstlane(row_ptr[row]);
        int end   = __builtin_amdgcn_readfirstlane(row_ptr[row + 1]);
        float acc = 0.0f;
        int j = start;
        for (; j + 8 <= end; j += 8) {
            int2 p[8]; float a[8];
            #pragma unroll
            for (int u = 0; u < 8; ++u) p[u] = pairs[j + u];
            #pragma unroll
            for (int u = 0; u < 8; ++u) a[u] = x[(size_t)p[u].x * D + lane];
            #pragma unroll
            for (int u = 0; u < 8; ++u) acc += __int_as_float(p[u].y) * a[u];
        }
        for (; j + 4 <= end; j += 4) {
            int2 p[4]; float a[4];
            #pragma unroll
            for (int u = 0; u < 4; ++u) p[u] = pairs[j + u];
            #pragma unroll
            for (int u = 0; u < 4; ++u) a[u] = x[(size_t)p[u].x * D + lane];
            #pragma unroll
            for (int u = 0; u < 4; ++u) acc += __int_as_float(p[u].y) * a[u];
        }
        for (; j < end; ++j) {
            int2 p = pairs[j];
            acc += __int_as_float(p.y) * x[(size_t)p.x * D + lane];
        }
        size_t base = (size_t)row * D;
        rep[base + lane] = acc + eps * x[base + lane];
    }
}

// ---------------- out = rep @ W + bias ----------------
#define GEMM_TM 64
__global__ __launch_bounds__(256) void k_gemm(
    const float* __restrict__ rep, const float* __restrict__ weight,
    const float* __restrict__ bias, float* __restrict__ out)
{
    __shared__ float rep_s[GEMM_TM * 68];
    __shared__ float Ws[D * D];
    int t = threadIdx.x;
    {
        const float4* w4 = (const float4*)weight;
        float4* s4 = (float4*)Ws;
        #pragma unroll
        for (int i = 0; i < (D * D / 4) / 256; ++i)
            s4[t + i * 256] = w4[t + i * 256];
    }
    int row0 = blockIdx.x * GEMM_TM;
    {
        const float4* r4 = (const float4*)rep;
        #pragma unroll
        for (int i = 0; i < 4; ++i) {
            int f = t + i * 256;
            int rr = f >> 4, kk4 = f & 15;
            float4 v = (row0 + rr < N_NODES) ? r4[(size_t)(row0 + rr) * 16 + kk4]
                                             : make_float4(0.f, 0.f, 0.f, 0.f);
            rep_s[rr * 68 + kk4 * 4 + 0] = v.x;
            rep_s[rr * 68 + kk4 * 4 + 1] = v.y;
            rep_s[rr * 68 + kk4 * 4 + 2] = v.z;
            rep_s[rr * 68 + kk4 * 4 + 3] = v.w;
        }
    }
    __syncthreads();

    int tx = t & 15, ty = t >> 4;
    float4 b4 = ((const float4*)bias)[tx];
    float acc[4][4];
    #pragma unroll
    for (int i = 0; i < 4; ++i) {
        acc[i][0] = b4.x; acc[i][1] = b4.y; acc[i][2] = b4.z; acc[i][3] = b4.w;
    }
    #pragma unroll 4
    for (int k4 = 0; k4 < 16; ++k4) {
        float4 rv[4];
        #pragma unroll
        for (int i = 0; i < 4; ++i)
            rv[i] = *(const float4*)&rep_s[(ty * 4 + i) * 68 + k4 * 4];
        #pragma unroll
        for (int kk = 0; kk < 4; ++kk) {
            float4 wv = *(const float4*)&Ws[(k4 * 4 + kk) * D + tx * 4];
            #pragma unroll
            for (int i = 0; i < 4; ++i) {
                float r = ((const float*)&rv[i])[kk];
                acc[i][0] += r * wv.x;
                acc[i][1] += r * wv.y;
                acc[i][2] += r * wv.z;
                acc[i][3] += r * wv.w;
            }
        }
    }
    #pragma unroll
    for (int i = 0; i < 4; ++i) {
        int row = row0 + ty * 4 + i;
        if (row < N_NODES)
            *(float4*)&out[(size_t)row * D + tx * 4] =
                make_float4(acc[i][0], acc[i][1], acc[i][2], acc[i][3]);
    }
}

extern "C" void kernel_launch(void* const* d_in, const int* in_sizes, int n_in,
                              void* d_out, int out_size, void* d_ws, size_t ws_size,
                              hipStream_t stream) {
    const float* x    = (const float*)d_in[0];
    const int*   esrc = (const int*)  d_in[1];
    const int*   edst = (const int*)  d_in[2];
    const float* ev   = (const float*)d_in[3];
    const float* w    = (const float*)d_in[4];
    const float* eps  = (const float*)d_in[5];
    const float* bias = (const float*)d_in[6];

    float* out = (float*)d_out;
    float* rep = out + (size_t)N_NODES * D;

    int* ws      = (int*)d_ws;
    int* cnt     = ws + WS_CNT;
    int* total   = ws + WS_TOTAL;
    int* row_ptr = ws + WS_ROWPTR;
    int* partial = ws + WS_PARTIAL;
    unsigned short* rank = (unsigned short*)(ws + WS_RANK);
    int2* pairs  = (int2*)(ws + WS_PAIRS);

    hipMemsetAsync(cnt, 0, (size_t)NCOPY * CSTRIDE * sizeof(int), stream);

    int hgrid = (N_EDGES + 256 * HIST_EPT - 1) / (256 * HIST_EPT);
    k_hist_rank<<<hgrid, 256, 0, stream>>>(esrc, cnt, rank);
    k_copy_scan<<<N_CHUNKS, SCAN_BLOCK, 0, stream>>>(cnt, total, partial);
    k_scan_partial<<<1, 128, 0, stream>>>(partial, row_ptr);
    k_chunk_scan<<<N_CHUNKS, SCAN_BLOCK, 0, stream>>>(total, partial, row_ptr, cnt);
    int fgrid = (N_EDGES + 256 * FILL_EPT - 1) / (256 * FILL_EPT);
    k_fill_rank<<<fgrid, 256, 0, stream>>>(esrc, edst, ev, cnt, rank, pairs);
    k_gather<<<GATHER_BLOCKS, 256, 0, stream>>>(x, row_ptr, pairs, eps, rep);
    k_gemm<<<(N_NODES + GEMM_TM - 1) / GEMM_TM, 256, 0, stream>>>(rep, w, bias, out);
}